// Round 3
// baseline (1370.994 us; speedup 1.0000x reference)
//
#include <hip/hip_runtime.h>

#define B_TOT 16384
#define T_STEPS 128
#define F_IN 29
#define K_HID 512
#define D_IN 32
#define NW 8        // waves per block
#define NT 4        // node tiles per wave (4*16 = 64 nodes/wave)
#define XS 33       // sX row stride (floats): frag-read bank = (m+8q+j)%32 -> <=2-way

typedef __attribute__((ext_vector_type(8))) short short8;   // 8 bf16 (MFMA A/B frag)
typedef __attribute__((ext_vector_type(4))) float floatx4;  // MFMA C/D frag

__device__ __forceinline__ float fast_tanh(float x) {
    float e = __expf(2.0f * x);
    return 1.0f - 2.0f * __builtin_amdgcn_rcpf(e + 1.0f);
}
__device__ __forceinline__ short bf16_hi_bits(float x) {
    return (short)(__float_as_uint(x) >> 16);
}
__device__ __forceinline__ float bf16_hi_f(float x) {
    return __uint_as_float(__float_as_uint(x) & 0xffff0000u);
}

// Block: 512 threads = 8 waves, owns 16 batch rows. Wave w owns nodes
// [64w, 64w+64) as 4 MFMA tiles; W1 frags (bf16 hi/lo) register-resident.
// X staged coalesced through double-buffered LDS, prefetched one step ahead.
__global__ __launch_bounds__(512, 6)
void narx_mfma2(const float* __restrict__ X,   // [B][T][29]
                const float* __restrict__ y0,  // [B][3]
                const float* __restrict__ W1,  // [32][512]
                const float* __restrict__ b1,  // [512]
                const float* __restrict__ W2,  // [512]
                const float* __restrict__ b2,  // [1]
                float* __restrict__ out)       // [B][T]
{
    __shared__ float sX[2][16][XS];      // 4224 B
    __shared__ float sPart[2][NW][16];   // 1024 B

    const int tid  = threadIdx.x;
    const int lane = tid & 63;
    const int w    = tid >> 6;     // 0..7
    const int q    = lane >> 4;    // 0..3
    const int m    = lane & 15;    // batch row (A) / node col (B)
    const size_t row = (size_t)blockIdx.x * 16 + m;

    // ---- one-time: W1 B-fragments (hi/lo), b1, W2 ----
    short8 whi[NT], wlo[NT];
    float b1v[NT], w2v[NT];
    #pragma unroll
    for (int nt = 0; nt < NT; ++nt) {
        int node = w * 64 + nt * 16 + m;
        #pragma unroll
        for (int j = 0; j < 8; ++j) {
            int k = q * 8 + j;
            float v  = W1[k * K_HID + node];
            float hf = bf16_hi_f(v);
            whi[nt][j] = bf16_hi_bits(v);
            wlo[nt][j] = bf16_hi_bits(v - hf);
        }
        b1v[nt] = b1[node];
        w2v[nt] = W2[node];
    }
    const float b2v = b2[0];

    float fb0 = y0[row * 3 + 0];
    float fb1 = y0[row * 3 + 1];
    float fb2 = y0[row * 3 + 2];

    // ---- X staging geometry: thread = (xr, xc), coalesced 116B row segments ----
    const int xr = tid >> 5;               // 0..15
    const int xc = tid & 31;               // 0..31
    const bool xact = (xc < F_IN);
    const float* Xbase = X + ((size_t)blockIdx.x * 16 + xr) * (T_STEPS * F_IN) + xc;

    // preload step 0
    if (xact) sX[0][xr][xc] = Xbase[0];
    __syncthreads();

    float4 pv = make_float4(0.f, 0.f, 0.f, 0.f);   // pred write-combine buffer

    for (int t = 0; t < T_STEPS; ++t) {
        const int cur = t & 1, nxt = cur ^ 1;

        // prefetch X(t+1) into a register (latency hides under this step's compute)
        const int tp = (t + 1 < T_STEPS) ? (t + 1) : (T_STEPS - 1);
        float xnew = 0.f;
        if (xact) xnew = Xbase[(size_t)tp * F_IN];

        // ---- build A fragment from LDS: A[m][k], k = q*8 + j ----
        float xv[8];
        #pragma unroll
        for (int j = 0; j < 8; ++j)
            xv[j] = sX[cur][m][q * 8 + j];        // k<=31 < XS, in-bounds
        if (q == 3) { xv[5] = fb0; xv[6] = fb1; xv[7] = fb2; }  // k=29,30,31

        short8 ahi, alo;
        #pragma unroll
        for (int j = 0; j < 8; ++j) {
            float hf = bf16_hi_f(xv[j]);
            ahi[j] = bf16_hi_bits(xv[j]);
            alo[j] = bf16_hi_bits(xv[j] - hf);
        }

        // ---- 4 node tiles: bf16x3 compensated MFMA + tanh + W2 partial ----
        float pa0 = 0.f, pa1 = 0.f, pa2 = 0.f, pa3 = 0.f;
        #pragma unroll
        for (int nt = 0; nt < NT; ++nt) {
            floatx4 c = {b1v[nt], b1v[nt], b1v[nt], b1v[nt]};
            c = __builtin_amdgcn_mfma_f32_16x16x32_bf16(ahi, whi[nt], c, 0, 0, 0);
            c = __builtin_amdgcn_mfma_f32_16x16x32_bf16(ahi, wlo[nt], c, 0, 0, 0);
            c = __builtin_amdgcn_mfma_f32_16x16x32_bf16(alo, whi[nt], c, 0, 0, 0);
            pa0 = fmaf(fast_tanh(c[0]), w2v[nt], pa0);
            pa1 = fmaf(fast_tanh(c[1]), w2v[nt], pa1);
            pa2 = fmaf(fast_tanh(c[2]), w2v[nt], pa2);
            pa3 = fmaf(fast_tanh(c[3]), w2v[nt], pa3);
        }

        // ---- reduce over 16 node cols (lane&15) ----
        #pragma unroll
        for (int mask = 1; mask <= 8; mask <<= 1) {
            pa0 += __shfl_xor(pa0, mask, 64);
            pa1 += __shfl_xor(pa1, mask, 64);
            pa2 += __shfl_xor(pa2, mask, 64);
            pa3 += __shfl_xor(pa3, mask, 64);
        }
        if (m == 0)   // lanes 0,16,32,48: rows q*4..q*4+3
            *(float4*)&sPart[cur][w][q * 4] = make_float4(pa0, pa1, pa2, pa3);

        // stash prefetched X (sX[nxt] last read before previous barrier -> safe)
        if (xact) sX[nxt][xr][xc] = xnew;

        __syncthreads();   // single barrier: publishes sPart[cur] and sX[nxt]

        // final pred for this lane's row m
        float pred = b2v;
        #pragma unroll
        for (int r = 0; r < NW; ++r) pred += sPart[cur][r][m];

        // write-combined output: one float4 store per 4 steps (w==0, lanes 0..15)
        pv = make_float4(pv.y, pv.z, pv.w, pred);
        if (w == 0 && lane < 16 && (t & 3) == 3)
            *(float4*)&out[row * T_STEPS + (t - 3)] = pv;

        fb2 = fb1; fb1 = fb0; fb0 = pred;
    }
}

extern "C" void kernel_launch(void* const* d_in, const int* in_sizes, int n_in,
                              void* d_out, int out_size, void* d_ws, size_t ws_size,
                              hipStream_t stream) {
    const float* X  = (const float*)d_in[0];
    const float* y0 = (const float*)d_in[1];
    const float* W1 = (const float*)d_in[2];
    const float* b1 = (const float*)d_in[3];
    const float* W2 = (const float*)d_in[4];
    const float* b2 = (const float*)d_in[5];
    float* out = (float*)d_out;

    dim3 grid(B_TOT / 16);   // 1024 blocks
    dim3 block(512);         // 8 waves
    narx_mfma2<<<grid, block, 0, stream>>>(X, y0, W1, b1, W2, b2, out);
}

// Round 4
// 810.487 us; speedup vs baseline: 1.6916x; 1.6916x over previous
//
#include <hip/hip_runtime.h>

#define B_TOT 16384
#define T_STEPS 128
#define F_IN 29
#define K_HID 512
#define D_IN 32
#define NTILE 32    // node tiles per wave = all 512 nodes
#define XS 33       // sX row stride (floats): frag-read banks <=2-way aliased (free)

typedef __attribute__((ext_vector_type(8))) short short8;   // 8 bf16 (MFMA A/B frag)
typedef __attribute__((ext_vector_type(4))) float floatx4;  // MFMA C/D frag

__device__ __forceinline__ float fast_tanh(float x) {
    float e = __expf(2.0f * x);
    return 1.0f - 2.0f * __builtin_amdgcn_rcpf(e + 1.0f);
}
__device__ __forceinline__ short bf16_hi_bits(float x) {
    return (short)(__float_as_uint(x) >> 16);
}
__device__ __forceinline__ float bf16_hi_f(float x) {
    return __uint_as_float(__float_as_uint(x) & 0xffff0000u);
}

// One wave (64 threads) per block; 1024 blocks = 1 wave per SIMD chip-wide.
// Wave owns 16 batch rows and ALL 512 hidden nodes (32 MFMA tiles, bf16x3).
// No __syncthreads anywhere: reduction + feedback routing are in-wave shuffles;
// X stages through a per-wave LDS ping-pong (wave-private, in-order DS pipe).
__global__ __launch_bounds__(64, 1)
void narx_wave(const float* __restrict__ X,   // [B][T][29]
               const float* __restrict__ y0,  // [B][3]
               const float* __restrict__ W1,  // [32][512]
               const float* __restrict__ b1,  // [512]
               const float* __restrict__ W2,  // [512]
               const float* __restrict__ b2,  // [1]
               float* __restrict__ out)       // [B][T]
{
    __shared__ float sX[2][16 * XS];   // 4224 B per block

    const int lane = threadIdx.x;      // 0..63
    const int q    = lane >> 4;        // 0..3
    const int m    = lane & 15;        // batch row (A/C) and node col (B)
    const size_t row0 = (size_t)blockIdx.x * 16;
    const size_t row  = row0 + m;

    // ---- one-time: W1 B-fragments (bf16 hi/lo), b1, W2 into registers ----
    // B[k][n]: n = lane&15, k = q*8 + j
    short8 whi[NTILE], wlo[NTILE];
    float b1v[NTILE], w2v[NTILE];
    #pragma unroll
    for (int nt = 0; nt < NTILE; ++nt) {
        int node = nt * 16 + m;
        #pragma unroll
        for (int j = 0; j < 8; ++j) {
            int k = q * 8 + j;
            float v  = W1[k * K_HID + node];
            float hf = bf16_hi_f(v);
            whi[nt][j] = bf16_hi_bits(v);
            wlo[nt][j] = bf16_hi_bits(v - hf);
        }
        b1v[nt] = b1[node];
        w2v[nt] = W2[node];
    }
    const float b2v = b2[0];

    // every lane tracks fb for its own row m
    float fb0 = y0[row * 3 + 0];
    float fb1 = y0[row * 3 + 1];
    float fb2 = y0[row * 3 + 2];

    // ---- X staging geometry: flat f = lane + 64*s over 16 rows x 29 cols ----
    const float* Xblk = X + row0 * (T_STEPS * F_IN);
    int  xoff[8], loff[8];
    bool xval[8];
    #pragma unroll
    for (int s = 0; s < 8; ++s) {
        int f = lane + 64 * s;
        int r = f / 29;            // magic-mul, one-time
        int c = f - r * 29;
        xval[s] = (f < 16 * F_IN);
        xoff[s] = r * (T_STEPS * F_IN) + c;
        loff[s] = r * XS + c;
    }

    // prefetch + publish step 0 (in-wave: ordering via lgkmcnt, no barrier)
    float xpre[8];
    #pragma unroll
    for (int s = 0; s < 8; ++s)
        if (xval[s]) xpre[s] = Xblk[xoff[s]];
    #pragma unroll
    for (int s = 0; s < 8; ++s)
        if (xval[s]) sX[0][loff[s]] = xpre[s];

    float4 pv = make_float4(0.f, 0.f, 0.f, 0.f);

    for (int t = 0; t < T_STEPS; ++t) {
        const int cur = t & 1;

        // A-frag reads first (LDS latency overlaps the prefetch issue below)
        float xv[8];
        const float* sxm = &sX[cur][m * XS];
        #pragma unroll
        for (int j = 0; j < 8; ++j)
            xv[j] = sxm[q * 8 + j];

        // prefetch X(t+1) into registers; drained at the ds_write at step end
        const int tn = (t + 1 < T_STEPS) ? (t + 1) : t;
        #pragma unroll
        for (int s = 0; s < 8; ++s)
            if (xval[s]) xpre[s] = Xblk[xoff[s] + tn * F_IN];

        if (q == 3) { xv[5] = fb0; xv[6] = fb1; xv[7] = fb2; }  // k = 29,30,31

        short8 ahi, alo;
        #pragma unroll
        for (int j = 0; j < 8; ++j) {
            float hf = bf16_hi_f(xv[j]);
            ahi[j] = bf16_hi_bits(xv[j]);
            alo[j] = bf16_hi_bits(xv[j] - hf);
        }

        // ---- 32 node tiles: bf16x3 MFMA + tanh + W2 partial ----
        float pa0 = 0.f, pa1 = 0.f, pa2 = 0.f, pa3 = 0.f;
        #pragma unroll
        for (int nt = 0; nt < NTILE; ++nt) {
            floatx4 c = {b1v[nt], b1v[nt], b1v[nt], b1v[nt]};
            c = __builtin_amdgcn_mfma_f32_16x16x32_bf16(ahi, whi[nt], c, 0, 0, 0);
            c = __builtin_amdgcn_mfma_f32_16x16x32_bf16(ahi, wlo[nt], c, 0, 0, 0);
            c = __builtin_amdgcn_mfma_f32_16x16x32_bf16(alo, whi[nt], c, 0, 0, 0);
            // C/D: col(node) = lane&15, row(batch) = q*4 + reg
            pa0 = fmaf(fast_tanh(c[0]), w2v[nt], pa0);
            pa1 = fmaf(fast_tanh(c[1]), w2v[nt], pa1);
            pa2 = fmaf(fast_tanh(c[2]), w2v[nt], pa2);
            pa3 = fmaf(fast_tanh(c[3]), w2v[nt], pa3);
        }

        // ---- reduce over the 16 node cols (lane bits 0..3) ----
        #pragma unroll
        for (int mask = 1; mask <= 8; mask <<= 1) {
            pa0 += __shfl_xor(pa0, mask, 64);
            pa1 += __shfl_xor(pa1, mask, 64);
            pa2 += __shfl_xor(pa2, mask, 64);
            pa3 += __shfl_xor(pa3, mask, 64);
        }
        // pa[reg] now = pred (sans b2) for batch row q*4+reg, replicated over m
        pa0 += b2v; pa1 += b2v; pa2 += b2v; pa3 += b2v;

        // ---- feedback routing: lane (q,m) needs pred of row m ----
        const int src = (m >> 2) << 4;   // a lane in quad group m>>2
        float t0 = __shfl(pa0, src, 64);
        float t1 = __shfl(pa1, src, 64);
        float t2 = __shfl(pa2, src, 64);
        float t3 = __shfl(pa3, src, 64);
        const int sel = m & 3;
        float predm = sel == 0 ? t0 : sel == 1 ? t1 : sel == 2 ? t2 : t3;
        fb2 = fb1; fb1 = fb0; fb0 = predm;

        // ---- write-combined output: lane (q, m<4) owns row q*4+m ----
        float psel = sel == 0 ? pa0 : sel == 1 ? pa1 : sel == 2 ? pa2 : pa3;
        pv = make_float4(pv.y, pv.z, pv.w, psel);
        if ((t & 3) == 3 && m < 4)
            *(float4*)&out[(row0 + q * 4 + m) * T_STEPS + (t - 3)] = pv;

        // ---- publish X(t+1) into the other buffer (waits vmcnt here) ----
        #pragma unroll
        for (int s = 0; s < 8; ++s)
            if (xval[s]) sX[cur ^ 1][loff[s]] = xpre[s];
    }
}

extern "C" void kernel_launch(void* const* d_in, const int* in_sizes, int n_in,
                              void* d_out, int out_size, void* d_ws, size_t ws_size,
                              hipStream_t stream) {
    const float* X  = (const float*)d_in[0];
    const float* y0 = (const float*)d_in[1];
    const float* W1 = (const float*)d_in[2];
    const float* b1 = (const float*)d_in[3];
    const float* W2 = (const float*)d_in[4];
    const float* b2 = (const float*)d_in[5];
    float* out = (float*)d_out;

    dim3 grid(B_TOT / 16);   // 1024 single-wave blocks = 1 wave/SIMD chip-wide
    dim3 block(64);
    narx_wave<<<grid, block, 0, stream>>>(X, y0, W1, b1, W2, b2, out);
}